// Round 4
// baseline (1051.107 us; speedup 1.0000x reference)
//
#include <hip/hip_runtime.h>
#include <hip/hip_bf16.h>

#define HID 100
#define TT 750
#define NB_TOT 1024
#define ALPHA 0.01f
#define NSTD 0.1f

typedef __bf16 bf16x8 __attribute__((ext_vector_type(8)));
typedef float floatx4 __attribute__((ext_vector_type(4)));
typedef float floatx16 __attribute__((ext_vector_type(16)));

__device__ __forceinline__ float fast_tanh(float v) {
    // tanh(v) = 1 - 2/(exp(2v)+1); graceful at +-inf, abs err ~1e-6
    float e = __expf(2.0f * v);
    return 1.0f - 2.0f / (e + 1.0f);
}

// Workgroup barrier WITHOUT the vmcnt(0) drain __syncthreads() emits:
// lgkmcnt(0) makes our ds ops visible; global prefetch stays in flight.
__device__ __forceinline__ void wg_barrier() {
    asm volatile("s_waitcnt lgkmcnt(0)" ::: "memory");
    __builtin_amdgcn_s_barrier();
    asm volatile("" ::: "memory");
    __builtin_amdgcn_sched_barrier(0);
}

__device__ __forceinline__ floatx16 zero16() {
    floatx16 z;
    #pragma unroll
    for (int i = 0; i < 16; ++i) z[i] = 0.f;
    return z;
}

struct Pf { float n0, n1; floatx4 u0, u1; };

__global__ __launch_bounds__(256, 2)
void rnn_kernel(const float* __restrict__ useq,   // [750][1024][4]
                const float* __restrict__ noise,  // [750][1024][100]
                const float* __restrict__ Jw,     // [100][100]
                const float* __restrict__ Bm,     // [4][100]
                const float* __restrict__ cxp,    // [100]
                const float* __restrict__ Ww,     // [100]
                const float* __restrict__ Wb,     // [1]
                float* __restrict__ out)          // [1024]
{
    // r state: double-buffered [buf][batch][k(pad 128)] bf16. Only rows 0,1
    // (the 2 batches) are real A-data; A rows 2..31 of the MFMA read row&1
    // (finite garbage is fine: C rows 2..31 are never consumed). k in
    // [100,112) stays ZERO (init, never overwritten) so J-pad zeros see 0.
    __shared__ __align__(16) __bf16 rbuf[2][2][128];
    __shared__ float red[2][112];

    const int tid  = threadIdx.x;
    const int wv   = tid >> 6;
    const int lane = tid & 63;
    const int l31  = lane & 31;
    const int g    = lane >> 5;          // k-subgroup (0: k 0-7, 1: k 8-15)
    const int wg   = blockIdx.x;
    const int gb0  = wg * 2;

    // wave wv owns N-tile wv: h = wv*32 + (lane&31)
    const int  hh  = wv * 32 + l31;
    const bool hv  = (hh < HID);
    const bool act = (g == 0) && hv;     // update lanes: 0..31 with valid h
    const int  hc  = hv ? hh : 0;

    // zero both r buffers: 2*2*128*2B = 1024 B = 256 dwords, one per thread
    ((float*)rbuf)[tid] = 0.0f;

    // --- J fragments (B operand), hi/lo bf16 split ---
    // B layout (32x32x16): col = lane&31 -> J row hh; k = c*16 + g*8 + j
    bf16x8 jhi[7], jlo[7];
    #pragma unroll
    for (int c = 0; c < 7; ++c) {
        bf16x8 vh, vl;
        #pragma unroll
        for (int j = 0; j < 8; ++j) {
            const int k = c * 16 + g * 8 + j;
            float v = (hv && k < HID) ? Jw[hc * HID + k] : 0.0f;
            __bf16 hi = (__bf16)v;
            vh[j] = hi;
            vl[j] = (__bf16)(v - (float)hi);
        }
        jhi[c] = vh; jlo[c] = vl;
    }

    floatx4 bm = {0,0,0,0};
    float cx = 0.f, w = 0.f;
    if (act) {
        bm = floatx4{Bm[0*HID+hh], Bm[1*HID+hh], Bm[2*HID+hh], Bm[3*HID+hh]};
        cx = cxp[hh]; w = Ww[hh];
    }

    // --- prefetch (depth 4): batch1 via immediate offsets (+400B / +16B) ---
    const float* npb = noise + (size_t)gb0 * HID + hc;   // + t*102400 floats
    const float* upb = useq  + (size_t)gb0 * 4;          // + t*4096 floats

    auto pfetch = [&](int t, Pf& P) {
        if (act) {
            const float* n = npb + (size_t)t * (NB_TOT * HID);
            const float* u = upb + (size_t)t * (NB_TOT * 4);
            P.n0 = n[0];  P.n1 = n[HID];          // +400 B imm offset
            P.u0 = *(const floatx4*)u;
            P.u1 = *(const floatx4*)(u + 4);      // +16 B imm offset
        }
    };

    Pf p0, p1, p2, p3;
    pfetch(0, p0); pfetch(1, p1); pfetch(2, p2); pfetch(3, p3);

    float x0 = 0.f, x1 = 0.f;
    __syncthreads();   // once before the loop

    // A-frag ds_read index (bf16x8 units): row = lane&1 (rows>=2 don't-care),
    // byte = row*256 + c*32 + g*16 -> only 4 distinct addrs/instr (broadcast)
    const int aidx = (lane & 1) * 16 + g;

    auto stepf = [&](int T, Pf& P, int pb) {
        // ---- A-frags: 7 x ds_read_b128, LDS-broadcast ----
        const bf16x8* rb = (const bf16x8*)(rbuf[pb]);
        bf16x8 afr[7];
        #pragma unroll
        for (int c = 0; c < 7; ++c) afr[c] = rb[aidx + c * 2];
        // ---- off-critical-path precompute (inputs are 4 steps old) ----
        float base0 = 0.f, base1 = 0.f;
        if (act) {
            const float d0 = P.u0[0]*bm[0] + P.u0[1]*bm[1] + P.u0[2]*bm[2] + P.u0[3]*bm[3];
            const float d1 = P.u1[0]*bm[0] + P.u1[1]*bm[1] + P.u1[2]*bm[2] + P.u1[3]*bm[3];
            base0 = x0 * (1.0f - ALPHA) + ALPHA * (d0 + cx + NSTD * P.n0);
            base1 = x1 * (1.0f - ALPHA) + ALPHA * (d1 + cx + NSTD * P.n1);
        }
        // ---- MFMA: 4 independent chains, depth <= 4 ----
        floatx16 hA = zero16(), hB = zero16(), lA = zero16(), lB = zero16();
        hA = __builtin_amdgcn_mfma_f32_32x32x16_bf16(afr[0], jhi[0], hA, 0, 0, 0);
        lA = __builtin_amdgcn_mfma_f32_32x32x16_bf16(afr[0], jlo[0], lA, 0, 0, 0);
        hB = __builtin_amdgcn_mfma_f32_32x32x16_bf16(afr[4], jhi[4], hB, 0, 0, 0);
        lB = __builtin_amdgcn_mfma_f32_32x32x16_bf16(afr[4], jlo[4], lB, 0, 0, 0);
        hA = __builtin_amdgcn_mfma_f32_32x32x16_bf16(afr[1], jhi[1], hA, 0, 0, 0);
        lA = __builtin_amdgcn_mfma_f32_32x32x16_bf16(afr[1], jlo[1], lA, 0, 0, 0);
        hB = __builtin_amdgcn_mfma_f32_32x32x16_bf16(afr[5], jhi[5], hB, 0, 0, 0);
        lB = __builtin_amdgcn_mfma_f32_32x32x16_bf16(afr[5], jlo[5], lB, 0, 0, 0);
        hA = __builtin_amdgcn_mfma_f32_32x32x16_bf16(afr[2], jhi[2], hA, 0, 0, 0);
        lA = __builtin_amdgcn_mfma_f32_32x32x16_bf16(afr[2], jlo[2], lA, 0, 0, 0);
        hB = __builtin_amdgcn_mfma_f32_32x32x16_bf16(afr[6], jhi[6], hB, 0, 0, 0);
        lB = __builtin_amdgcn_mfma_f32_32x32x16_bf16(afr[6], jlo[6], lB, 0, 0, 0);
        hA = __builtin_amdgcn_mfma_f32_32x32x16_bf16(afr[3], jhi[3], hA, 0, 0, 0);
        lA = __builtin_amdgcn_mfma_f32_32x32x16_bf16(afr[3], jlo[3], lA, 0, 0, 0);
        // ---- update: C rows 0,1 = regs 0,1 on lanes 0..31 ----
        if (act) {
            const float y0 = (hA[0] + hB[0]) + (lA[0] + lB[0]);
            const float y1 = (hA[1] + hB[1]) + (lA[1] + lB[1]);
            x0 = base0 + ALPHA * y0;
            x1 = base1 + ALPHA * y1;
            __bf16* wb = (__bf16*)(rbuf[pb ^ 1]);
            wb[hh]       = (__bf16)fast_tanh(x0);
            wb[128 + hh] = (__bf16)fast_tanh(x1);
        }
        // ---- refill prefetch slot (uniform guard; linear t for strength
        // reduction; loads stay in flight across wg_barrier) ----
        const int tf = T + 4;
        if (tf < TT) pfetch(tf, P);
        wg_barrier();   // ONE barrier per step
    };

    for (int tb = 0; tb < 748; tb += 4) {
        stepf(tb + 0, p0, 0);
        stepf(tb + 1, p1, 1);
        stepf(tb + 2, p2, 0);
        stepf(tb + 3, p3, 1);
    }
    stepf(748, p0, 0);
    stepf(749, p1, 1);

    // ---- epilogue: out[b] = sum_h tanh(x_final)*Wout[h] + Wout_b ----
    if (act) {
        red[0][hh] = fast_tanh(x0) * w;
        red[1][hh] = fast_tanh(x1) * w;
    }
    __syncthreads();
    if (tid < 2) {
        float s2 = Wb[0];
        #pragma unroll 4
        for (int i = 0; i < HID; ++i) s2 += red[tid][i];
        out[gb0 + tid] = s2;
    }
}

extern "C" void kernel_launch(void* const* d_in, const int* in_sizes, int n_in,
                              void* d_out, int out_size, void* d_ws, size_t ws_size,
                              hipStream_t stream) {
    rnn_kernel<<<dim3(512), dim3(256), 0, stream>>>(
        (const float*)d_in[0], (const float*)d_in[1], (const float*)d_in[2],
        (const float*)d_in[3], (const float*)d_in[4], (const float*)d_in[5],
        (const float*)d_in[6], (float*)d_out);
}

// Round 5
// 763.582 us; speedup vs baseline: 1.3765x; 1.3765x over previous
//
#include <hip/hip_runtime.h>
#include <hip/hip_bf16.h>

#define HID 100
#define TT 750
#define NB_TOT 1024
#define ALPHA 0.01f
#define NSTD 0.1f

typedef __bf16 bf16x8 __attribute__((ext_vector_type(8)));
typedef float floatx4 __attribute__((ext_vector_type(4)));

__device__ __forceinline__ float fast_tanh(float v) {
    // tanh(v) = 1 - 2/(exp(2v)+1); graceful at +-inf, abs err ~1e-6
    float e = __expf(2.0f * v);
    return 1.0f - 2.0f / (e + 1.0f);
}

// Workgroup barrier WITHOUT the vmcnt(0) drain __syncthreads() emits:
// lgkmcnt(0) makes our ds ops visible; global prefetch stays in flight.
// Essential at 1 block/CU: the t+4 noise prefetch must survive 8 barriers.
__device__ __forceinline__ void wg_barrier() {
    asm volatile("s_waitcnt lgkmcnt(0)" ::: "memory");
    __builtin_amdgcn_s_barrier();
    asm volatile("" ::: "memory");
    __builtin_amdgcn_sched_barrier(0);
}

struct Pf { float n0, n2; floatx4 u0, u2; };   // batches bb and bb+2

__global__ __launch_bounds__(256, 1)
void rnn_kernel(const float* __restrict__ useq,   // [750][1024][4]
                const float* __restrict__ noise,  // [750][1024][100]
                const float* __restrict__ Jw,     // [100][100]
                const float* __restrict__ Bm,     // [4][100]
                const float* __restrict__ cxp,    // [100]
                const float* __restrict__ Ww,     // [100]
                const float* __restrict__ Wb,     // [1]
                float* __restrict__ out)          // [1024]
{
    // r buffer: 16 rows (M) x 128 bf16 (K padded), 16B-chunk XOR swizzle.
    // Rows 0-3 = batches 0-3 (4 batches/block amortizes the M=16 padding:
    // MFMA cost per block-step is independent of how many rows are real).
    // Rows 4-15 and k>=100 stay zero forever.
    __shared__ __align__(16) __bf16 rbuf[16 * 128];
    __shared__ float ybuf[4][112];
    __shared__ float red[4][112];

    const int tid  = threadIdx.x;
    const int wv   = tid >> 6;
    const int lane = tid & 63;
    const int wg   = blockIdx.x;

    // --- update-thread mapping: tid<200 -> (bb in {0,1}, hh); each thread
    // updates batches bb and bb+2 (2 tanh/thread, spread over 200 threads) ---
    const int  bb  = tid / 100;
    const int  hh  = tid % 100;
    const bool upd = (tid < 200);
    const int  gb  = wg * 4 + bb;   // global batches gb and gb+2

    float bm0=0.f, bm1=0.f, bm2=0.f, bm3=0.f, cx=0.f, wout=0.f;
    if (upd) {
        bm0 = Bm[0*HID + hh]; bm1 = Bm[1*HID + hh];
        bm2 = Bm[2*HID + hh]; bm3 = Bm[3*HID + hh];
        cx  = cxp[hh];
        wout = Ww[hh];
    }

    // zero rbuf (16*128*2B = 4096 B = 256 x 16B)
    {
        floatx4 z = {0.f, 0.f, 0.f, 0.f};
        ((floatx4*)rbuf)[tid] = z;
    }

    // --- preload J fragments (B-operand layout), split hi/lo bf16 ---
    // wave w owns N-tiles {2w, 2w+1}; tile 7 is a dummy (all zero, no writeback)
    const int m16 = lane & 15;
    const int q   = lane >> 4;
    bf16x8 jhi[2][4], jlo[2][4];
    #pragma unroll
    for (int ti = 0; ti < 2; ++ti) {
        const int tile = wv * 2 + ti;
        const int h = tile * 16 + m16;     // B n-index -> J row h
        #pragma unroll
        for (int s = 0; s < 4; ++s) {
            bf16x8 vhi, vlo;
            #pragma unroll
            for (int j = 0; j < 8; ++j) {
                const int k = s * 32 + q * 8 + j;
                float v = (h < HID && k < HID) ? Jw[h * HID + k] : 0.0f;
                __bf16 hi = (__bf16)v;
                vhi[j] = hi;
                vlo[j] = (__bf16)(v - (float)hi);
            }
            jhi[ti][s] = vhi;
            jlo[ti][s] = vlo;
        }
    }

    // --- prefetch pipeline (depth 4): batch bb+2 via imm offsets (+800B/+32B) ---
    const float* np = noise + (size_t)gb * HID + hh;   // + t*102400
    const float* up = useq  + (size_t)gb * 4;          // + t*4096

    auto pfetch = [&](int t, Pf& P) {
        if (upd) {
            const float* n = np + (size_t)t * (NB_TOT * HID);
            const float* u = up + (size_t)t * (NB_TOT * 4);
            P.n0 = n[0];
            P.n2 = n[2 * HID];                 // +800 B imm offset
            P.u0 = *(const floatx4*)u;
            P.u2 = *(const floatx4*)(u + 8);   // +32 B imm offset
        }
    };

    Pf p0, p1, p2, p3;
    pfetch(0, p0); pfetch(1, p1); pfetch(2, p2); pfetch(3, p3);

    float x0 = 0.0f, x2 = 0.0f;
    __syncthreads();

    auto step = [&](int T, Pf& P) {
        // ---- Phase A: y_t = r_t @ J^T via MFMA ----
        bf16x8 afr[4];
        const bf16x8* rb16 = (const bf16x8*)rbuf;
        #pragma unroll
        for (int s = 0; s < 4; ++s)
            afr[s] = rb16[m16 * 16 + ((s * 4 + q) ^ (lane & 7))];
        #pragma unroll
        for (int ti = 0; ti < 2; ++ti) {
            // independent hi/lo 4-deep chains, joined by adds
            floatx4 acch = {0.f, 0.f, 0.f, 0.f};
            floatx4 accl = {0.f, 0.f, 0.f, 0.f};
            #pragma unroll
            for (int s = 0; s < 4; ++s) {
                acch = __builtin_amdgcn_mfma_f32_16x16x32_bf16(afr[s], jhi[ti][s], acch, 0, 0, 0);
                accl = __builtin_amdgcn_mfma_f32_16x16x32_bf16(afr[s], jlo[ti][s], accl, 0, 0, 0);
            }
            const int tile = wv * 2 + ti;
            // C-layout: col = lane&15, row = (lane>>4)*4 + reg -> lanes 0..15
            // hold rows 0..3 in regs 0..3 = batches 0..3.
            if (tile < 7 && lane < 16) {
                ybuf[0][tile * 16 + lane] = acch[0] + accl[0];
                ybuf[1][tile * 16 + lane] = acch[1] + accl[1];
                ybuf[2][tile * 16 + lane] = acch[2] + accl[2];
                ybuf[3][tile * 16 + lane] = acch[3] + accl[3];
            }
        }
        wg_barrier();
        // ---- Phase B: x updates for batches bb and bb+2 ----
        if (upd) {
            const float y0 = ybuf[bb][hh];
            const float y2 = ybuf[bb + 2][hh];
            const float d0 = P.u0[0]*bm0 + P.u0[1]*bm1 + P.u0[2]*bm2 + P.u0[3]*bm3;
            const float d2 = P.u2[0]*bm0 + P.u2[1]*bm1 + P.u2[2]*bm2 + P.u2[3]*bm3;
            x0 = x0 * (1.0f - ALPHA) + ALPHA * (y0 + d0 + cx + NSTD * P.n0);
            x2 = x2 * (1.0f - ALPHA) + ALPHA * (y2 + d2 + cx + NSTD * P.n2);
            // A-layout write, chunk swizzle: physical chunk = (hh>>3) ^ row
            // (read side XORs lane&7 = row&7, consistent for rows 0..3)
            const int c = hh >> 3, e = hh & 7;
            rbuf[ bb      * 128 + ((c ^  bb     ) << 3) + e] = (__bf16)fast_tanh(x0);
            rbuf[(bb + 2) * 128 + ((c ^ (bb + 2)) << 3) + e] = (__bf16)fast_tanh(x2);
            // prefetch t+4 — stays in flight across wg_barrier (no vmcnt drain)
            const int tf = (T + 4 < TT) ? (T + 4) : (TT - 1);
            pfetch(tf, P);
        }
        wg_barrier();
    };

    for (int tb = 0; tb < 748; tb += 4) {
        step(tb + 0, p0);
        step(tb + 1, p1);
        step(tb + 2, p2);
        step(tb + 3, p3);
    }
    step(748, p0);
    step(749, p1);

    // ---- epilogue: out[b] = sum_h tanh(x_final) * Wout[h] + Wout_b ----
    if (upd) {
        red[bb][hh]     = fast_tanh(x0) * wout;
        red[bb + 2][hh] = fast_tanh(x2) * wout;
    }
    __syncthreads();
    if (tid < 4) {
        float s2 = Wb[0];
        #pragma unroll 4
        for (int i = 0; i < HID; ++i) s2 += red[tid][i];
        out[wg * 4 + tid] = s2;
    }
}

extern "C" void kernel_launch(void* const* d_in, const int* in_sizes, int n_in,
                              void* d_out, int out_size, void* d_ws, size_t ws_size,
                              hipStream_t stream) {
    rnn_kernel<<<dim3(256), dim3(256), 0, stream>>>(
        (const float*)d_in[0], (const float*)d_in[1], (const float*)d_in[2],
        (const float*)d_in[3], (const float*)d_in[4], (const float*)d_in[5],
        (const float*)d_in[6], (float*)d_out);
}